// Round 14
// baseline (655.224 us; speedup 1.0000x reference)
//
#include <hip/hip_runtime.h>

#define LAYERS 2
#define DIM 1024
#define HEADS 16
#define HD 64
#define BATCH 2
#define SEQ 1024
#define ROWS (BATCH * SEQ) /* 2048 */
#define FFN (4 * DIM)      /* 4096 */
#define VOCAB 32000
#define QKVN (3 * DIM) /* 3072 */

typedef unsigned short u16;
typedef short vshort8 __attribute__((ext_vector_type(8)));
typedef float f32x4 __attribute__((ext_vector_type(4)));

#define VMCNT(n) asm volatile("s_waitcnt vmcnt(" #n ")" ::: "memory")

__device__ __forceinline__ u16 f2bf(float f) {
  union { float f; unsigned u; } x{f};
  unsigned r = (x.u + 0x7fffu + ((x.u >> 16) & 1u)) >> 16;
  return (u16)r;
}

__device__ __forceinline__ void gll16(const void* g, u16* l) {
  __builtin_amdgcn_global_load_lds(
      (const __attribute__((address_space(1))) void*)g,
      (__attribute__((address_space(3))) void*)l, 16, 0, 0);
}

// bijective XCD swizzle (m204)
__device__ __forceinline__ int xcd_swizzle(int orig, int nwg) {
  int q = nwg >> 3, r = nwg & 7;
  int xcd = orig & 7;
  int base = (xcd < r) ? xcd * (q + 1) : r * (q + 1) + (xcd - r) * q;
  return base + (orig >> 3);
}

// ---------------- 64x64 transpose: f32 [.,C] tile -> bf16 [.,R] tile ----------------
__device__ __forceinline__ void trans64(const float* __restrict__ src,
                                        u16* __restrict__ dst, int C, int R,
                                        int r0, int c0, int tid,
                                        u16 (*tl)[72]) {
  int lr = tid >> 4, lc4 = (tid & 15) * 4;
#pragma unroll
  for (int i = 0; i < 4; i++) {
    int row = lr + i * 16;
    float4 v = *(const float4*)&src[(size_t)(r0 + row) * C + c0 + lc4];
    ushort4 o{f2bf(v.x), f2bf(v.y), f2bf(v.z), f2bf(v.w)};
    *(ushort4*)&tl[row][lc4] = o;
  }
  __syncthreads();
#pragma unroll
  for (int i = 0; i < 2; i++) {
    int idx = tid + i * 256;
    int ci = idx >> 3, ri0 = (idx & 7) * 8;
    vshort8 o;
#pragma unroll
    for (int j = 0; j < 8; j++) o[j] = (short)tl[ri0 + j][ci];
    *(vshort8*)&dst[(size_t)(c0 + ci) * R + r0 + ri0] = o;
  }
}

// ---------------- prologue mega-kernel: transposes + bias pack + embed+norm ----------------
__global__ __launch_bounds__(256) void prologue_kernel(
    const float* __restrict__ wq, const float* __restrict__ wk,
    const float* __restrict__ wv, const float* __restrict__ wo,
    const float* __restrict__ w1, const float* __restrict__ w2,
    const float* __restrict__ head_w, const float* __restrict__ bq,
    const float* __restrict__ bk, const float* __restrict__ bv,
    const int* __restrict__ ids, const float* __restrict__ emb,
    const float* __restrict__ g1, u16* __restrict__ wqkvT,
    u16* __restrict__ woT, u16* __restrict__ w1T, u16* __restrict__ w2T,
    u16* __restrict__ headT, float* __restrict__ bqkv, float* __restrict__ x,
    u16* __restrict__ h) {
  __shared__ u16 tl[64][72];
  __shared__ float part[4];
  int bid = blockIdx.x, tid = threadIdx.x;
  if (bid >= 6144 && bid < 6168) {
    int t = (bid - 6144) * 256 + tid;
    int l = t / QKVN, c = t % QKVN;
    float v;
    if (c < DIM) v = bq[l * DIM + c];
    else if (c < 2 * DIM) v = bk[l * DIM + c - DIM];
    else v = bv[l * DIM + c - 2 * DIM];
    bqkv[(size_t)l * QKVN + c] = v;
    return;
  }
  if (bid >= 6168 && bid < 8216) {
    int row = bid - 6168;
    int id = ids[row];
    float4 v = ((const float4*)(emb + (size_t)id * DIM))[tid];
    ((float4*)(x + (size_t)row * DIM))[tid] = v;
    float ss = v.x * v.x + v.y * v.y + v.z * v.z + v.w * v.w;
    for (int off = 32; off > 0; off >>= 1) ss += __shfl_down(ss, off);
    if ((tid & 63) == 0) part[tid >> 6] = ss;
    __syncthreads();
    float tot = part[0] + part[1] + part[2] + part[3];
    float r = rsqrtf(tot / (float)DIM + 1e-6f);
    float4 gv = ((const float4*)g1)[tid];
    ushort4 o;
    o.x = f2bf(v.x * r * gv.x);
    o.y = f2bf(v.y * r * gv.y);
    o.z = f2bf(v.z * r * gv.z);
    o.w = f2bf(v.w * r * gv.w);
    *(ushort4*)(h + (size_t)row * DIM + tid * 4) = o;
    return;
  }
  const float* src;
  u16* dst;
  int R, C, r0, c0;
  if (bid < 2048) {
    int job = bid >> 8, tile = bid & 255;
    int l = job >> 2, wsel = job & 3;
    src = (wsel == 0 ? wq : wsel == 1 ? wk : wsel == 2 ? wv : wo) +
          (size_t)l * DIM * DIM;
    dst = (wsel < 3)
              ? wqkvT + (size_t)l * QKVN * DIM + (size_t)wsel * DIM * DIM
              : woT + (size_t)l * DIM * DIM;
    R = DIM; C = DIM;
    c0 = (tile & 15) * 64; r0 = (tile >> 4) * 64;
  } else if (bid < 4096) {
    int idx = bid - 2048;
    int l = idx >> 10, t = idx & 1023;
    src = w1 + (size_t)l * DIM * FFN;
    dst = w1T + (size_t)l * DIM * FFN;
    R = DIM; C = FFN;
    c0 = (t & 63) * 64; r0 = (t >> 6) * 64;
  } else if (bid < 6144) {
    int idx = bid - 4096;
    int l = idx >> 10, t = idx & 1023;
    src = w2 + (size_t)l * FFN * DIM;
    dst = w2T + (size_t)l * FFN * DIM;
    R = FFN; C = DIM;
    c0 = (t & 15) * 64; r0 = (t >> 4) * 64;
  } else {
    int t = bid - 8216;
    src = head_w; dst = headT;
    R = DIM; C = VOCAB;
    c0 = (t % 500) * 64; r0 = (t / 500) * 64;
  }
  trans64(src, dst, C, R, r0, c0, tid, tl);
}

// ---------------- addnorm: x += sum(P[0..NP)) + bias; h = rmsnorm(x,g) ----------------
template <int NP>
__global__ __launch_bounds__(256) void addnorm_kernel(
    float* __restrict__ x, const float* __restrict__ P,
    const float* __restrict__ bias, const float* __restrict__ g,
    u16* __restrict__ h) {
  int row = blockIdx.x;
  int t = threadIdx.x;
  float4 v = ((const float4*)(x + (size_t)row * DIM))[t];
  float4 c = ((const float4*)bias)[t];
  v.x += c.x; v.y += c.y; v.z += c.z; v.w += c.w;
#pragma unroll
  for (int p = 0; p < NP; p++) {
    float4 a = ((const float4*)(P + (size_t)p * ROWS * DIM + (size_t)row * DIM))[t];
    v.x += a.x; v.y += a.y; v.z += a.z; v.w += a.w;
  }
  ((float4*)(x + (size_t)row * DIM))[t] = v;
  float ss = v.x * v.x + v.y * v.y + v.z * v.z + v.w * v.w;
  for (int off = 32; off > 0; off >>= 1) ss += __shfl_down(ss, off);
  __shared__ float part[4];
  if ((t & 63) == 0) part[t >> 6] = ss;
  __syncthreads();
  float tot = part[0] + part[1] + part[2] + part[3];
  float r = rsqrtf(tot / (float)DIM + 1e-6f);
  float4 gv = ((const float4*)g)[t];
  ushort4 o;
  o.x = f2bf(v.x * r * gv.x);
  o.y = f2bf(v.y * r * gv.y);
  o.z = f2bf(v.z * r * gv.z);
  o.w = f2bf(v.w * r * gv.w);
  *(ushort4*)(h + (size_t)row * DIM + t * 4) = o;
}

// ---------------- 256x128 triple-buffered GEMM (K must be 1024) ----------------
// 8 waves (4Mx2N), 88 VGPR, 144KB LDS -> but per-instance buffers sized for
// 2 blocks/CU when NMT==1 path is used with this geometry. Triple-buffer:
// stage(g+2) at top of K-tile, single VMCNT(6) per K-tile (~3.5 phase slack).
template <int NMT, int OUTF32, int SILU, int VT>
__global__ __launch_bounds__(512, 2) void gemm256x128p_kernel(
    const u16* __restrict__ A, const u16* __restrict__ Wt,
    const float* __restrict__ bias, void* __restrict__ outv,
    u16* __restrict__ vt2, int M, int N, int K) {
  __shared__ u16 As[3][256 * 64];
  __shared__ u16 Bs[3][128 * 64];
  int nm = M >> 8, nn = N >> 7;
  int nwg = (NMT == 1) ? nm * nn : nn;
  int wg = xcd_swizzle(blockIdx.x, nwg);
  int mi0, ni;
  if (NMT == 1) { mi0 = wg % nm; ni = wg / nm; }
  else          { mi0 = 0; ni = wg; }
  int n0 = ni << 7;
  int tid = threadIdx.x, w = tid >> 6, lane = tid & 63;
  int wr = w >> 1, wc = w & 1;
  int r16 = lane & 15, g4 = lane >> 4;
  int srow8 = lane >> 3, sslot = lane & 7;
  const int NG = NMT * 16;

  f32x4 acc[4][4] = {};

  auto stage = [&](int g) {
    int buf = g % 3;
    int kt = g & 15;
    int mb = (mi0 + (g >> 4)) << 8;
#pragma unroll
    for (int j = 0; j < 4; j++) {
      int chunk = j * 8 + w;
      int row = chunk * 8 + srow8;
      int slot = sslot ^ (row & 7);
      gll16(A + (size_t)(mb + row) * K + kt * 64 + slot * 8,
            &As[buf][chunk * 512 + lane * 8]);
    }
#pragma unroll
    for (int j = 0; j < 2; j++) {
      int chunk = j * 8 + w;
      int row = chunk * 8 + srow8;
      int slot = sslot ^ (row & 7);
      gll16(Wt + (size_t)(n0 + row) * K + kt * 64 + slot * 8,
            &Bs[buf][chunk * 512 + lane * 8]);
    }
  };
  auto readA = [&](int buf, int mf, int kk) -> vshort8 {
    int row = wr * 64 + mf * 16 + r16;
    int slot = (kk * 4 + g4) ^ (row & 7);
    return *(const vshort8*)&As[buf][row * 64 + slot * 8];
  };
  auto readB = [&](int buf, int nf, int kk) -> vshort8 {
    int row = wc * 64 + nf * 16 + r16;
    int slot = (kk * 4 + g4) ^ (row & 7);
    return *(const vshort8*)&Bs[buf][row * 64 + slot * 8];
  };

  stage(0);
  stage(1);
  VMCNT(6);
  __builtin_amdgcn_s_barrier();

  vshort8 af[4][2], bf0[2][2], bf1[2][2];

  for (int mt = 0; mt < NMT; mt++) {
    for (int kt = 0; kt < 16; kt++) {
      int g = mt * 16 + kt;
      int buf = g % 3;
#pragma unroll
      for (int m = 0; m < 4; m++)
#pragma unroll
        for (int kk = 0; kk < 2; kk++) af[m][kk] = readA(buf, m, kk);
#pragma unroll
      for (int n = 0; n < 2; n++)
#pragma unroll
        for (int kk = 0; kk < 2; kk++) bf0[n][kk] = readB(buf, n, kk);
      bool staged = (g + 2 < NG);
      if (staged) stage(g + 2);
      __builtin_amdgcn_s_barrier();
      __builtin_amdgcn_s_setprio(1);
#pragma unroll
      for (int m = 0; m < 4; m++)
#pragma unroll
        for (int n = 0; n < 2; n++)
#pragma unroll
          for (int kk = 0; kk < 2; kk++)
            acc[m][n] = __builtin_amdgcn_mfma_f32_16x16x32_bf16(
                af[m][kk], bf0[n][kk], acc[m][n], 0, 0, 0);
      __builtin_amdgcn_s_setprio(0);
      __builtin_amdgcn_s_barrier();
#pragma unroll
      for (int n = 0; n < 2; n++)
#pragma unroll
        for (int kk = 0; kk < 2; kk++) bf1[n][kk] = readB(buf, 2 + n, kk);
      __builtin_amdgcn_s_barrier();
      __builtin_amdgcn_s_setprio(1);
#pragma unroll
      for (int m = 0; m < 4; m++)
#pragma unroll
        for (int n = 0; n < 2; n++)
#pragma unroll
          for (int kk = 0; kk < 2; kk++)
            acc[m][n + 2] = __builtin_amdgcn_mfma_f32_16x16x32_bf16(
                af[m][kk], bf1[n][kk], acc[m][n + 2], 0, 0, 0);
      __builtin_amdgcn_s_setprio(0);
      if (staged) { VMCNT(6); } else { VMCNT(0); }
      __builtin_amdgcn_s_barrier();
    }
    int m0e = (mi0 + mt) << 8;
#pragma unroll
    for (int m = 0; m < 4; m++) {
      int rowb = m0e + wr * 64 + m * 16 + g4 * 4;
#pragma unroll
      for (int n = 0; n < 4; n++) {
        int col = n0 + wc * 64 + n * 16 + r16;
        float b = bias[col];
        if (OUTF32) {
#pragma unroll
          for (int j = 0; j < 4; j++)
            ((float*)outv)[(size_t)(rowb + j) * N + col] = acc[m][n][j] + b;
        } else {
          u16 ov[4];
#pragma unroll
          for (int j = 0; j < 4; j++) {
            float v = acc[m][n][j] + b;
            if (SILU) v = v / (1.f + __expf(-v));
            ov[j] = f2bf(v);
          }
          if (VT && col >= 2 * DIM) {
            int dv = col - 2 * DIM;
            int hh = dv >> 6, dd = dv & 63;
            int bb = rowb >> 10, s = rowb & 1023;
            ushort4 o4{ov[0], ov[1], ov[2], ov[3]};
            *(ushort4*)&vt2[((((size_t)(bb * 16 + hh) * (SEQ / 8) + (s >> 3)) *
                                  64 + dd) * 8) + (s & 7)] = o4;
          } else {
#pragma unroll
            for (int j = 0; j < 4; j++)
              ((u16*)outv)[(size_t)(rowb + j) * N + col] = ov[j];
          }
        }
        if (NMT > 1) acc[m][n] = f32x4{0.f, 0.f, 0.f, 0.f};
      }
    }
  }
}

// ---------------- GEMM 128x128, double-buffered 2-phase, NS-way split-K ----------------
template <int NS>
__global__ __launch_bounds__(256, 2) void gemm128sk_kernel(
    const u16* __restrict__ A, const u16* __restrict__ Wt,
    float* __restrict__ P, int M, int N, int K) {
  __shared__ u16 As[2][128 * 64];
  __shared__ u16 Bs[2][128 * 64];
  int nm = M >> 7, nn = N >> 7, nwg = nm * nn;
  int wg = xcd_swizzle(blockIdx.x, nwg * NS);
  int ks = wg / nwg;
  wg -= ks * nwg;
  int ni = wg % nn, mi = wg / nn;
  int m0 = mi << 7, n0 = ni << 7;
  int kb = ks * (K / NS);
  int NTt = (K / NS) >> 6;
  int tid = threadIdx.x, wave = tid >> 6, lane = tid & 63;
  int wr = wave >> 1, wc = wave & 1;
  int r16 = lane & 15, g4 = lane >> 4;
  int lrow = lane >> 3, lslot = lane & 7;

  f32x4 acc[4][4] = {};

  auto stage = [&](int buf, int kt) {
#pragma unroll
    for (int i = 0; i < 4; i++) {
      int s = wave * 4 + i;
      int row = s * 8 + lrow;
      int slot = lslot ^ (row & 7);
      gll16(A + (size_t)(m0 + row) * K + kb + kt * 64 + slot * 8,
            &As[buf][s * 512 + lane * 8]);
    }
#pragma unroll
    for (int i = 0; i < 4; i++) {
      int s = wave * 4 + i;
      int row = s * 8 + lrow;
      int slot = lslot ^ (row & 7);
      gll16(Wt + (size_t)(n0 + row) * K + kb + kt * 64 + slot * 8,
            &Bs[buf][s * 512 + lane * 8]);
    }
  };

  stage(0, 0);
  VMCNT(0);
  __builtin_amdgcn_s_barrier();

  for (int t = 0; t < NTt; t++) {
    int cur = t & 1;
    if (t + 1 < NTt) stage(cur ^ 1, t + 1);
#pragma unroll
    for (int kk = 0; kk < 2; kk++) {
      vshort8 af[4], bf[4];
#pragma unroll
      for (int m = 0; m < 4; m++) {
        int r = wr * 64 + m * 16 + r16;
        int slot = (kk * 4 + g4) ^ (r & 7);
        af[m] = *(const vshort8*)&As[cur][r * 64 + slot * 8];
      }
#pragma unroll
      for (int n = 0; n < 4; n++) {
        int c = wc * 64 + n * 16 + r16;
        int slot = (kk * 4 + g4) ^ (c & 7);
        bf[n] = *(const vshort8*)&Bs[cur][c * 64 + slot * 8];
      }
#pragma unroll
      for (int m = 0; m < 4; m++)
#pragma unroll
        for (int n = 0; n < 4; n++)
          acc[m][n] = __builtin_amdgcn_mfma_f32_16x16x32_bf16(af[m], bf[n],
                                                              acc[m][n], 0, 0, 0);
    }
    VMCNT(0);
    __builtin_amdgcn_s_barrier();
  }

  float* Pk = P + (size_t)ks * M * N;
#pragma unroll
  for (int m = 0; m < 4; m++) {
    int rowb = m0 + wr * 64 + m * 16 + g4 * 4;
#pragma unroll
    for (int n = 0; n < 4; n++) {
      int col = n0 + wc * 64 + n * 16 + r16;
#pragma unroll
      for (int j = 0; j < 4; j++)
        Pk[(size_t)(rowb + j) * N + col] = acc[m][n][j];
    }
  }
}

// ---------------- flash attention: 4-wave blocks, LDS-staged K ----------------
__global__ __launch_bounds__(256) void attn_kernel(const u16* __restrict__ qkv,
                                                   const u16* __restrict__ vt2,
                                                   u16* __restrict__ o) {
  __shared__ u16 Ks[2][32 * 64];
  __shared__ u16 pl[4][16 * 40];
  int qblk = blockIdx.x, bh = blockIdx.y;
  int b = bh >> 4, h = bh & 15;
  int tid = threadIdx.x, w = tid >> 6, lane = tid & 63;
  int r16 = lane & 15, g4 = lane >> 4;
  int q0 = qblk * 64 + w * 16;

  const u16* qrow = qkv + ((size_t)(b * SEQ) + q0 + r16) * QKVN + h * HD;
  vshort8 aq0 = *(const vshort8*)(qrow + g4 * 8);
  vshort8 aq1 = *(const vshort8*)(qrow + 32 + g4 * 8);

  float mrun[4], lrun[4];
  f32x4 accO[4];
#pragma unroll
  for (int j = 0; j < 4; j++) { mrun[j] = -1e30f; lrun[j] = 0.f; }
#pragma unroll
  for (int d = 0; d < 4; d++) accO[d] = f32x4{0.f, 0.f, 0.f, 0.f};

  int nkvT = qblk * 2 + 2;
  auto stageK = [&](int buf, int kt) {
    int row = tid >> 3;
    int slot = (tid & 7) ^ (row & 7);
    gll16(qkv + ((size_t)(b * SEQ) + kt * 32 + row) * QKVN + DIM + h * HD + slot * 8,
          &Ks[buf][w * 512 + lane * 8]);
  };
  stageK(0, 0);
  __syncthreads();
  int buf = 0;
  for (int kt = 0; kt < nkvT; kt++) {
    int kv0 = kt * 32;
    if (kt + 1 < nkvT) stageK(buf ^ 1, kt + 1);
    if (kv0 <= q0 + 15) {
      int row0 = r16, row1 = 16 + r16;
      vshort8 bk00 = *(const vshort8*)&Ks[buf][row0 * 64 + ((0 + g4) ^ (row0 & 7)) * 8];
      vshort8 bk01 = *(const vshort8*)&Ks[buf][row0 * 64 + ((4 + g4) ^ (row0 & 7)) * 8];
      vshort8 bk10 = *(const vshort8*)&Ks[buf][row1 * 64 + ((0 + g4) ^ (row1 & 7)) * 8];
      vshort8 bk11 = *(const vshort8*)&Ks[buf][row1 * 64 + ((4 + g4) ^ (row1 & 7)) * 8];
      f32x4 s0 = {}, s1 = {};
      s0 = __builtin_amdgcn_mfma_f32_16x16x32_bf16(aq0, bk00, s0, 0, 0, 0);
      s0 = __builtin_amdgcn_mfma_f32_16x16x32_bf16(aq1, bk01, s0, 0, 0, 0);
      s1 = __builtin_amdgcn_mfma_f32_16x16x32_bf16(aq0, bk10, s1, 0, 0, 0);
      s1 = __builtin_amdgcn_mfma_f32_16x16x32_bf16(aq1, bk11, s1, 0, 0, 0);

#pragma unroll
      for (int j = 0; j < 4; j++) {
        int qg = q0 + g4 * 4 + j;
        float x0 = s0[j] * 0.125f;
        float x1 = s1[j] * 0.125f;
        if (kv0 + r16 > qg) x0 = -1e30f;
        if (kv0 + 16 + r16 > qg) x1 = -1e30f;
        float mx = fmaxf(x0, x1);
#pragma unroll
        for (int mm = 1; mm < 16; mm <<= 1) mx = fmaxf(mx, __shfl_xor(mx, mm));
        float mnew = fmaxf(mrun[j], mx);
        float alpha = __expf(mrun[j] - mnew);
        float p0 = __expf(x0 - mnew);
        float p1 = __expf(x1 - mnew);
        float rs = p0 + p1;
#pragma unroll
        for (int mm = 1; mm < 16; mm <<= 1) rs += __shfl_xor(rs, mm);
        lrun[j] = lrun[j] * alpha + rs;
        mrun[j] = mnew;
#pragma unroll
        for (int d = 0; d < 4; d++) accO[d][j] *= alpha;
        pl[w][(g4 * 4 + j) * 40 + r16] = f2bf(p0);
        pl[w][(g4 * 4 + j) * 40 + 16 + r16] = f2bf(p1);
      }
      asm volatile("s_waitcnt lgkmcnt(0)" ::: "memory");
      vshort8 ap = *(const vshort8*)&pl[w][r16 * 40 + g4 * 8];
      const u16* vbase = vt2 + (((size_t)bh * (SEQ / 8) + (kv0 >> 3) + g4) * 64) * 8;
#pragma unroll
      for (int d = 0; d < 4; d++) {
        vshort8 bv = *(const vshort8*)(vbase + (size_t)(d * 16 + r16) * 8);
        accO[d] = __builtin_amdgcn_mfma_f32_16x16x32_bf16(ap, bv, accO[d], 0, 0, 0);
      }
    }
    __syncthreads();
    buf ^= 1;
  }

#pragma unroll
  for (int j = 0; j < 4; j++) {
    float inv = 1.f / lrun[j];
    int row = q0 + g4 * 4 + j;
#pragma unroll
    for (int d = 0; d < 4; d++)
      o[((size_t)(b * SEQ) + row) * DIM + h * HD + d * 16 + r16] =
          f2bf(accO[d][j] * inv);
  }
}

// ---------------- host ----------------
extern "C" void kernel_launch(void* const* d_in, const int* in_sizes, int n_in,
                              void* d_out, int out_size, void* d_ws,
                              size_t ws_size, hipStream_t stream) {
  const int* ids = (const int*)d_in[0];
  const float* emb = (const float*)d_in[1];
  const float* g1 = (const float*)d_in[2];
  const float* wq = (const float*)d_in[3];
  const float* bq = (const float*)d_in[4];
  const float* wk = (const float*)d_in[5];
  const float* bk = (const float*)d_in[6];
  const float* wv = (const float*)d_in[7];
  const float* bv = (const float*)d_in[8];
  const float* wo = (const float*)d_in[9];
  const float* bo = (const float*)d_in[10];
  const float* g2 = (const float*)d_in[11];
  const float* w1 = (const float*)d_in[12];
  const float* b1 = (const float*)d_in[13];
  const float* w2 = (const float*)d_in[14];
  const float* b2 = (const float*)d_in[15];
  const float* gf = (const float*)d_in[16];
  const float* head_w = (const float*)d_in[17];
  const float* head_b = (const float*)d_in[18];
  float* out = (float*)d_out;

  char* ws = (char*)d_ws;
  size_t off = 0;
  auto alloc = [&](size_t bytes) -> char* {
    char* p = ws + off;
    off += (bytes + 255) & ~(size_t)255;
    return p;
  };
  u16* wqkvT = (u16*)alloc((size_t)LAYERS * QKVN * DIM * 2);
  u16* woT = (u16*)alloc((size_t)LAYERS * DIM * DIM * 2);
  u16* w1T = (u16*)alloc((size_t)LAYERS * DIM * FFN * 2);
  u16* w2T = (u16*)alloc((size_t)LAYERS * DIM * FFN * 2);
  u16* headT = (u16*)alloc((size_t)VOCAB * DIM * 2);
  float* bqkv = (float*)alloc((size_t)LAYERS * QKVN * 4);
  float* x = (float*)alloc((size_t)ROWS * DIM * 4);
  u16* h = (u16*)alloc((size_t)ROWS * DIM * 2);
  u16* qkvb = (u16*)alloc((size_t)ROWS * QKVN * 2);
  u16* vtb = (u16*)alloc((size_t)ROWS * DIM * 2);
  u16* ob = (u16*)alloc((size_t)ROWS * DIM * 2);
  u16* tb = (u16*)alloc((size_t)ROWS * FFN * 2);
  float* P = (float*)alloc((size_t)4 * ROWS * DIM * 4);
  if (off > ws_size) return;

  prologue_kernel<<<16216, 256, 0, stream>>>(
      wq, wk, wv, wo, w1, w2, head_w, bq, bk, bv, ids, emb, g1, wqkvT, woT,
      w1T, w2T, headT, bqkv, x, h);

  for (int l = 0; l < LAYERS; l++) {
    gemm256x128p_kernel<1, 0, 0, 1>
        <<<(ROWS / 256) * (QKVN / 128), 512, 0, stream>>>(
            h, wqkvT + (size_t)l * QKVN * DIM, bqkv + (size_t)l * QKVN,
            qkvb, vtb, ROWS, QKVN, DIM);
    attn_kernel<<<dim3(SEQ / 64, BATCH * HEADS), 256, 0, stream>>>(qkvb, vtb, ob);
    gemm128sk_kernel<4>
        <<<4 * (ROWS / 128) * (DIM / 128), 256, 0, stream>>>(
            ob, woT + (size_t)l * DIM * DIM, P, ROWS, DIM, DIM);
    addnorm_kernel<4><<<ROWS, 256, 0, stream>>>(
        x, P, bo + (size_t)l * DIM, g2 + (size_t)l * DIM, h);
    gemm256x128p_kernel<1, 0, 1, 0>
        <<<(ROWS / 256) * (FFN / 128), 512, 0, stream>>>(
            h, w1T + (size_t)l * DIM * FFN, b1 + (size_t)l * FFN, tb, nullptr,
            ROWS, FFN, DIM);
    gemm128sk_kernel<4>
        <<<4 * (ROWS / 128) * (DIM / 128), 256, 0, stream>>>(
            tb, w2T + (size_t)l * DIM * FFN, P, ROWS, DIM, FFN);
    addnorm_kernel<4><<<ROWS, 256, 0, stream>>>(
        x, P, b2 + (size_t)l * DIM,
        (l == LAYERS - 1) ? gf : (g1 + (size_t)(l + 1) * DIM), h);
  }
  // head: 256x128 tile, NMT=1, 2000 blocks (m-fastest), 2 blocks/CU.
  gemm256x128p_kernel<1, 1, 0, 0>
      <<<(ROWS / 256) * (VOCAB / 128), 512, 0, stream>>>(
          h, headT, head_b, out, nullptr, ROWS, VOCAB, DIM);
}

// Round 15
// 557.553 us; speedup vs baseline: 1.1752x; 1.1752x over previous
//
#include <hip/hip_runtime.h>

#define LAYERS 2
#define DIM 1024
#define HEADS 16
#define HD 64
#define BATCH 2
#define SEQ 1024
#define ROWS (BATCH * SEQ) /* 2048 */
#define FFN (4 * DIM)      /* 4096 */
#define VOCAB 32000
#define QKVN (3 * DIM) /* 3072 */

typedef unsigned short u16;
typedef short vshort8 __attribute__((ext_vector_type(8)));
typedef float f32x4 __attribute__((ext_vector_type(4)));

#define VMCNT(n) asm volatile("s_waitcnt vmcnt(" #n ")" ::: "memory")

__device__ __forceinline__ u16 f2bf(float f) {
  union { float f; unsigned u; } x{f};
  unsigned r = (x.u + 0x7fffu + ((x.u >> 16) & 1u)) >> 16;
  return (u16)r;
}

__device__ __forceinline__ void gll16(const void* g, u16* l) {
  __builtin_amdgcn_global_load_lds(
      (const __attribute__((address_space(1))) void*)g,
      (__attribute__((address_space(3))) void*)l, 16, 0, 0);
}

// bijective XCD swizzle (m204)
__device__ __forceinline__ int xcd_swizzle(int orig, int nwg) {
  int q = nwg >> 3, r = nwg & 7;
  int xcd = orig & 7;
  int base = (xcd < r) ? xcd * (q + 1) : r * (q + 1) + (xcd - r) * q;
  return base + (orig >> 3);
}

// ---------------- 64x64 transpose: f32 [.,C] tile -> bf16 [.,R] tile ----------------
__device__ __forceinline__ void trans64(const float* __restrict__ src,
                                        u16* __restrict__ dst, int C, int R,
                                        int r0, int c0, int tid,
                                        u16 (*tl)[72]) {
  int lr = tid >> 4, lc4 = (tid & 15) * 4;
#pragma unroll
  for (int i = 0; i < 4; i++) {
    int row = lr + i * 16;
    float4 v = *(const float4*)&src[(size_t)(r0 + row) * C + c0 + lc4];
    ushort4 o{f2bf(v.x), f2bf(v.y), f2bf(v.z), f2bf(v.w)};
    *(ushort4*)&tl[row][lc4] = o;
  }
  __syncthreads();
#pragma unroll
  for (int i = 0; i < 2; i++) {
    int idx = tid + i * 256;
    int ci = idx >> 3, ri0 = (idx & 7) * 8;
    vshort8 o;
#pragma unroll
    for (int j = 0; j < 8; j++) o[j] = (short)tl[ri0 + j][ci];
    *(vshort8*)&dst[(size_t)(c0 + ci) * R + r0 + ri0] = o;
  }
}

// ---------------- prologue mega-kernel: transposes + bias pack + embed+norm ----------------
__global__ __launch_bounds__(256) void prologue_kernel(
    const float* __restrict__ wq, const float* __restrict__ wk,
    const float* __restrict__ wv, const float* __restrict__ wo,
    const float* __restrict__ w1, const float* __restrict__ w2,
    const float* __restrict__ head_w, const float* __restrict__ bq,
    const float* __restrict__ bk, const float* __restrict__ bv,
    const int* __restrict__ ids, const float* __restrict__ emb,
    const float* __restrict__ g1, u16* __restrict__ wqkvT,
    u16* __restrict__ woT, u16* __restrict__ w1T, u16* __restrict__ w2T,
    u16* __restrict__ headT, float* __restrict__ bqkv, float* __restrict__ x,
    u16* __restrict__ h) {
  __shared__ u16 tl[64][72];
  __shared__ float part[4];
  int bid = blockIdx.x, tid = threadIdx.x;
  if (bid >= 6144 && bid < 6168) {
    int t = (bid - 6144) * 256 + tid;
    int l = t / QKVN, c = t % QKVN;
    float v;
    if (c < DIM) v = bq[l * DIM + c];
    else if (c < 2 * DIM) v = bk[l * DIM + c - DIM];
    else v = bv[l * DIM + c - 2 * DIM];
    bqkv[(size_t)l * QKVN + c] = v;
    return;
  }
  if (bid >= 6168 && bid < 8216) {
    int row = bid - 6168;
    int id = ids[row];
    float4 v = ((const float4*)(emb + (size_t)id * DIM))[tid];
    ((float4*)(x + (size_t)row * DIM))[tid] = v;
    float ss = v.x * v.x + v.y * v.y + v.z * v.z + v.w * v.w;
    for (int off = 32; off > 0; off >>= 1) ss += __shfl_down(ss, off);
    if ((tid & 63) == 0) part[tid >> 6] = ss;
    __syncthreads();
    float tot = part[0] + part[1] + part[2] + part[3];
    float r = rsqrtf(tot / (float)DIM + 1e-6f);
    float4 gv = ((const float4*)g1)[tid];
    ushort4 o;
    o.x = f2bf(v.x * r * gv.x);
    o.y = f2bf(v.y * r * gv.y);
    o.z = f2bf(v.z * r * gv.z);
    o.w = f2bf(v.w * r * gv.w);
    *(ushort4*)(h + (size_t)row * DIM + tid * 4) = o;
    return;
  }
  const float* src;
  u16* dst;
  int R, C, r0, c0;
  if (bid < 2048) {
    int job = bid >> 8, tile = bid & 255;
    int l = job >> 2, wsel = job & 3;
    src = (wsel == 0 ? wq : wsel == 1 ? wk : wsel == 2 ? wv : wo) +
          (size_t)l * DIM * DIM;
    dst = (wsel < 3)
              ? wqkvT + (size_t)l * QKVN * DIM + (size_t)wsel * DIM * DIM
              : woT + (size_t)l * DIM * DIM;
    R = DIM; C = DIM;
    c0 = (tile & 15) * 64; r0 = (tile >> 4) * 64;
  } else if (bid < 4096) {
    int idx = bid - 2048;
    int l = idx >> 10, t = idx & 1023;
    src = w1 + (size_t)l * DIM * FFN;
    dst = w1T + (size_t)l * DIM * FFN;
    R = DIM; C = FFN;
    c0 = (t & 63) * 64; r0 = (t >> 6) * 64;
  } else if (bid < 6144) {
    int idx = bid - 4096;
    int l = idx >> 10, t = idx & 1023;
    src = w2 + (size_t)l * FFN * DIM;
    dst = w2T + (size_t)l * FFN * DIM;
    R = FFN; C = DIM;
    c0 = (t & 15) * 64; r0 = (t >> 4) * 64;
  } else {
    int t = bid - 8216;
    src = head_w; dst = headT;
    R = DIM; C = VOCAB;
    c0 = (t % 500) * 64; r0 = (t / 500) * 64;
  }
  trans64(src, dst, C, R, r0, c0, tid, tl);
}

// ---------------- addnorm: x += sum(P[0..NP)) + bias; h = rmsnorm(x,g) ----------------
template <int NP>
__global__ __launch_bounds__(256) void addnorm_kernel(
    float* __restrict__ x, const float* __restrict__ P,
    const float* __restrict__ bias, const float* __restrict__ g,
    u16* __restrict__ h) {
  int row = blockIdx.x;
  int t = threadIdx.x;
  float4 v = ((const float4*)(x + (size_t)row * DIM))[t];
  float4 c = ((const float4*)bias)[t];
  v.x += c.x; v.y += c.y; v.z += c.z; v.w += c.w;
#pragma unroll
  for (int p = 0; p < NP; p++) {
    float4 a = ((const float4*)(P + (size_t)p * ROWS * DIM + (size_t)row * DIM))[t];
    v.x += a.x; v.y += a.y; v.z += a.z; v.w += a.w;
  }
  ((float4*)(x + (size_t)row * DIM))[t] = v;
  float ss = v.x * v.x + v.y * v.y + v.z * v.z + v.w * v.w;
  for (int off = 32; off > 0; off >>= 1) ss += __shfl_down(ss, off);
  __shared__ float part[4];
  if ((t & 63) == 0) part[t >> 6] = ss;
  __syncthreads();
  float tot = part[0] + part[1] + part[2] + part[3];
  float r = rsqrtf(tot / (float)DIM + 1e-6f);
  float4 gv = ((const float4*)g)[t];
  ushort4 o;
  o.x = f2bf(v.x * r * gv.x);
  o.y = f2bf(v.y * r * gv.y);
  o.z = f2bf(v.z * r * gv.z);
  o.w = f2bf(v.w * r * gv.w);
  *(ushort4*)(h + (size_t)row * DIM + t * 4) = o;
}

// ---------------- 256x128 triple-buffered GEMM (K must be 1024; qkv/w1) ----------------
template <int NMT, int OUTF32, int SILU, int VT>
__global__ __launch_bounds__(512, 2) void gemm256x128p_kernel(
    const u16* __restrict__ A, const u16* __restrict__ Wt,
    const float* __restrict__ bias, void* __restrict__ outv,
    u16* __restrict__ vt2, int M, int N, int K) {
  __shared__ u16 As[3][256 * 64];
  __shared__ u16 Bs[3][128 * 64];
  int nm = M >> 8, nn = N >> 7;
  int nwg = (NMT == 1) ? nm * nn : nn;
  int wg = xcd_swizzle(blockIdx.x, nwg);
  int mi0, ni;
  if (NMT == 1) { mi0 = wg % nm; ni = wg / nm; }
  else          { mi0 = 0; ni = wg; }
  int n0 = ni << 7;
  int tid = threadIdx.x, w = tid >> 6, lane = tid & 63;
  int wr = w >> 1, wc = w & 1;
  int r16 = lane & 15, g4 = lane >> 4;
  int srow8 = lane >> 3, sslot = lane & 7;
  const int NG = NMT * 16;

  f32x4 acc[4][4] = {};

  auto stage = [&](int g) {
    int buf = g % 3;
    int kt = g & 15;
    int mb = (mi0 + (g >> 4)) << 8;
#pragma unroll
    for (int j = 0; j < 4; j++) {
      int chunk = j * 8 + w;
      int row = chunk * 8 + srow8;
      int slot = sslot ^ (row & 7);
      gll16(A + (size_t)(mb + row) * K + kt * 64 + slot * 8,
            &As[buf][chunk * 512 + lane * 8]);
    }
#pragma unroll
    for (int j = 0; j < 2; j++) {
      int chunk = j * 8 + w;
      int row = chunk * 8 + srow8;
      int slot = sslot ^ (row & 7);
      gll16(Wt + (size_t)(n0 + row) * K + kt * 64 + slot * 8,
            &Bs[buf][chunk * 512 + lane * 8]);
    }
  };
  auto readA = [&](int buf, int mf, int kk) -> vshort8 {
    int row = wr * 64 + mf * 16 + r16;
    int slot = (kk * 4 + g4) ^ (row & 7);
    return *(const vshort8*)&As[buf][row * 64 + slot * 8];
  };
  auto readB = [&](int buf, int nf, int kk) -> vshort8 {
    int row = wc * 64 + nf * 16 + r16;
    int slot = (kk * 4 + g4) ^ (row & 7);
    return *(const vshort8*)&Bs[buf][row * 64 + slot * 8];
  };

  stage(0);
  stage(1);
  VMCNT(6);
  __builtin_amdgcn_s_barrier();

  vshort8 af[4][2], bf0[2][2], bf1[2][2];

  for (int mt = 0; mt < NMT; mt++) {
    for (int kt = 0; kt < 16; kt++) {
      int g = mt * 16 + kt;
      int buf = g % 3;
#pragma unroll
      for (int m = 0; m < 4; m++)
#pragma unroll
        for (int kk = 0; kk < 2; kk++) af[m][kk] = readA(buf, m, kk);
#pragma unroll
      for (int n = 0; n < 2; n++)
#pragma unroll
        for (int kk = 0; kk < 2; kk++) bf0[n][kk] = readB(buf, n, kk);
      bool staged = (g + 2 < NG);
      if (staged) stage(g + 2);
      __builtin_amdgcn_s_barrier();
      __builtin_amdgcn_s_setprio(1);
#pragma unroll
      for (int m = 0; m < 4; m++)
#pragma unroll
        for (int n = 0; n < 2; n++)
#pragma unroll
          for (int kk = 0; kk < 2; kk++)
            acc[m][n] = __builtin_amdgcn_mfma_f32_16x16x32_bf16(
                af[m][kk], bf0[n][kk], acc[m][n], 0, 0, 0);
      __builtin_amdgcn_s_setprio(0);
      __builtin_amdgcn_s_barrier();
#pragma unroll
      for (int n = 0; n < 2; n++)
#pragma unroll
        for (int kk = 0; kk < 2; kk++) bf1[n][kk] = readB(buf, 2 + n, kk);
      __builtin_amdgcn_s_barrier();
      __builtin_amdgcn_s_setprio(1);
#pragma unroll
      for (int m = 0; m < 4; m++)
#pragma unroll
        for (int n = 0; n < 2; n++)
#pragma unroll
          for (int kk = 0; kk < 2; kk++)
            acc[m][n + 2] = __builtin_amdgcn_mfma_f32_16x16x32_bf16(
                af[m][kk], bf1[n][kk], acc[m][n + 2], 0, 0, 0);
      __builtin_amdgcn_s_setprio(0);
      if (staged) { VMCNT(6); } else { VMCNT(0); }
      __builtin_amdgcn_s_barrier();
    }
    int m0e = (mi0 + mt) << 8;
#pragma unroll
    for (int m = 0; m < 4; m++) {
      int rowb = m0e + wr * 64 + m * 16 + g4 * 4;
#pragma unroll
      for (int n = 0; n < 4; n++) {
        int col = n0 + wc * 64 + n * 16 + r16;
        float b = bias[col];
        if (OUTF32) {
#pragma unroll
          for (int j = 0; j < 4; j++)
            ((float*)outv)[(size_t)(rowb + j) * N + col] = acc[m][n][j] + b;
        } else {
          u16 ov[4];
#pragma unroll
          for (int j = 0; j < 4; j++) {
            float v = acc[m][n][j] + b;
            if (SILU) v = v / (1.f + __expf(-v));
            ov[j] = f2bf(v);
          }
          if (VT && col >= 2 * DIM) {
            int dv = col - 2 * DIM;
            int hh = dv >> 6, dd = dv & 63;
            int bb = rowb >> 10, s = rowb & 1023;
            ushort4 o4{ov[0], ov[1], ov[2], ov[3]};
            *(ushort4*)&vt2[((((size_t)(bb * 16 + hh) * (SEQ / 8) + (s >> 3)) *
                                  64 + dd) * 8) + (s & 7)] = o4;
          } else {
#pragma unroll
            for (int j = 0; j < 4; j++)
              ((u16*)outv)[(size_t)(rowb + j) * N + col] = ov[j];
          }
        }
        if (NMT > 1) acc[m][n] = f32x4{0.f, 0.f, 0.f, 0.f};
      }
    }
  }
}

// ---------------- GEMM 128x128, double-buffered 2-phase, NS-way split-K ----------------
template <int NS>
__global__ __launch_bounds__(256, 2) void gemm128sk_kernel(
    const u16* __restrict__ A, const u16* __restrict__ Wt,
    float* __restrict__ P, int M, int N, int K) {
  __shared__ u16 As[2][128 * 64];
  __shared__ u16 Bs[2][128 * 64];
  int nm = M >> 7, nn = N >> 7, nwg = nm * nn;
  int wg = xcd_swizzle(blockIdx.x, nwg * NS);
  int ks = wg / nwg;
  wg -= ks * nwg;
  int ni = wg % nn, mi = wg / nn;
  int m0 = mi << 7, n0 = ni << 7;
  int kb = ks * (K / NS);
  int NTt = (K / NS) >> 6;
  int tid = threadIdx.x, wave = tid >> 6, lane = tid & 63;
  int wr = wave >> 1, wc = wave & 1;
  int r16 = lane & 15, g4 = lane >> 4;
  int lrow = lane >> 3, lslot = lane & 7;

  f32x4 acc[4][4] = {};

  auto stage = [&](int buf, int kt) {
#pragma unroll
    for (int i = 0; i < 4; i++) {
      int s = wave * 4 + i;
      int row = s * 8 + lrow;
      int slot = lslot ^ (row & 7);
      gll16(A + (size_t)(m0 + row) * K + kb + kt * 64 + slot * 8,
            &As[buf][s * 512 + lane * 8]);
    }
#pragma unroll
    for (int i = 0; i < 4; i++) {
      int s = wave * 4 + i;
      int row = s * 8 + lrow;
      int slot = lslot ^ (row & 7);
      gll16(Wt + (size_t)(n0 + row) * K + kb + kt * 64 + slot * 8,
            &Bs[buf][s * 512 + lane * 8]);
    }
  };

  stage(0, 0);
  VMCNT(0);
  __builtin_amdgcn_s_barrier();

  for (int t = 0; t < NTt; t++) {
    int cur = t & 1;
    if (t + 1 < NTt) stage(cur ^ 1, t + 1);
#pragma unroll
    for (int kk = 0; kk < 2; kk++) {
      vshort8 af[4], bf[4];
#pragma unroll
      for (int m = 0; m < 4; m++) {
        int r = wr * 64 + m * 16 + r16;
        int slot = (kk * 4 + g4) ^ (r & 7);
        af[m] = *(const vshort8*)&As[cur][r * 64 + slot * 8];
      }
#pragma unroll
      for (int n = 0; n < 4; n++) {
        int c = wc * 64 + n * 16 + r16;
        int slot = (kk * 4 + g4) ^ (c & 7);
        bf[n] = *(const vshort8*)&Bs[cur][c * 64 + slot * 8];
      }
#pragma unroll
      for (int m = 0; m < 4; m++)
#pragma unroll
        for (int n = 0; n < 4; n++)
          acc[m][n] = __builtin_amdgcn_mfma_f32_16x16x32_bf16(af[m], bf[n],
                                                              acc[m][n], 0, 0, 0);
    }
    VMCNT(0);
    __builtin_amdgcn_s_barrier();
  }

  float* Pk = P + (size_t)ks * M * N;
#pragma unroll
  for (int m = 0; m < 4; m++) {
    int rowb = m0 + wr * 64 + m * 16 + g4 * 4;
#pragma unroll
    for (int n = 0; n < 4; n++) {
      int col = n0 + wc * 64 + n * 16 + r16;
#pragma unroll
      for (int j = 0; j < 4; j++)
        Pk[(size_t)(rowb + j) * N + col] = acc[m][n][j];
    }
  }
}

// ---------------- persistent 256x256 head GEMM, 3-phase/K-tile (r8/r12) ----------------
__global__ __launch_bounds__(512, 2) void gemm256p_kernel(
    const u16* __restrict__ A, const u16* __restrict__ Wt,
    const float* __restrict__ bias, float* __restrict__ out,
    int M, int N, int K) {
  __shared__ u16 As[2][256 * 64];
  __shared__ u16 Bs[2][256 * 64];
  int nn = N >> 8;
  int wg = xcd_swizzle(blockIdx.x, nn * 2);
  int ni = wg >> 1, mhalf = wg & 1;
  int n0 = ni << 8;
  int tid = threadIdx.x, w = tid >> 6, lane = tid & 63;
  int wr = w >> 2, wc = w & 3;
  int r16 = lane & 15, g4 = lane >> 4;
  int srow8 = lane >> 3, sslot = lane & 7;
  const int NTK = 16;
  const int NGT = 64;

  f32x4 acc[8][4] = {};

  auto stageA = [&](int buf, int mb, int kt, int hb, int j) {
    int chunk = j * 8 + w;
    int row = hb * 128 + chunk * 8 + srow8;
    int slot = sslot ^ (row & 7);
    gll16(A + (size_t)(mb + row) * K + kt * 64 + slot * 8,
          &As[buf][hb * 8192 + chunk * 512 + lane * 8]);
  };
  auto stageB = [&](int buf, int kt, int hb, int j) {
    int chunk = j * 8 + w;
    int row = hb * 128 + chunk * 8 + srow8;
    int slot = sslot ^ (row & 7);
    gll16(Wt + (size_t)(n0 + row) * K + kt * 64 + slot * 8,
          &Bs[buf][hb * 8192 + chunk * 512 + lane * 8]);
  };
  auto readA = [&](int buf, int mf, int kk) -> vshort8 {
    int row = mf * 32 + wr * 16 + r16;
    int slot = (kk * 4 + g4) ^ (row & 7);
    return *(const vshort8*)&As[buf][row * 64 + slot * 8];
  };
  auto readB = [&](int buf, int nf, int kk) -> vshort8 {
    int row = nf * 64 + wc * 16 + r16;
    int slot = (kk * 4 + g4) ^ (row & 7);
    return *(const vshort8*)&Bs[buf][row * 64 + slot * 8];
  };

  int mb0 = (mhalf * 4) << 8;
  stageA(0, mb0, 0, 0, 0); stageA(0, mb0, 0, 0, 1);
  stageB(0, 0, 0, 0);      stageB(0, 0, 0, 1);
  stageB(0, 0, 1, 0);      stageB(0, 0, 1, 1);
  stageA(0, mb0, 0, 1, 0); stageA(0, mb0, 0, 1, 1);
  VMCNT(4);
  __builtin_amdgcn_s_barrier();

  vshort8 af[4][2], bf0[2][2], bf1[2][2];

  for (int ti = 0; ti < 4; ti++) {
    int m0 = (mhalf * 4 + ti) << 8;
    for (int tt = 0; tt < NTK; tt++) {
      int gt = ti * NTK + tt;
      int cur = gt & 1, nxt = cur ^ 1;
      int gt1 = gt + 1;
      bool hn = gt1 < NGT;
      int kt1 = gt1 & (NTK - 1);
      int mb1 = (mhalf * 4 + (gt1 >> 4)) << 8;
      // ---- p0 ----
#pragma unroll
      for (int m = 0; m < 4; m++)
#pragma unroll
        for (int kk = 0; kk < 2; kk++) af[m][kk] = readA(cur, m, kk);
#pragma unroll
      for (int n = 0; n < 2; n++)
#pragma unroll
        for (int kk = 0; kk < 2; kk++) bf0[n][kk] = readB(cur, n, kk);
      if (hn) {
        stageA(nxt, mb1, kt1, 0, 0); stageA(nxt, mb1, kt1, 0, 1);
        stageB(nxt, kt1, 0, 0);      stageB(nxt, kt1, 0, 1);
      }
      __builtin_amdgcn_s_barrier();
      __builtin_amdgcn_s_setprio(1);
#pragma unroll
      for (int m = 0; m < 4; m++)
#pragma unroll
        for (int n = 0; n < 2; n++)
#pragma unroll
          for (int kk = 0; kk < 2; kk++)
            acc[m][n] = __builtin_amdgcn_mfma_f32_16x16x32_bf16(
                af[m][kk], bf0[n][kk], acc[m][n], 0, 0, 0);
      __builtin_amdgcn_s_setprio(0);
      VMCNT(4);
      __builtin_amdgcn_s_barrier();
      // ---- p1 ----
#pragma unroll
      for (int n = 0; n < 2; n++)
#pragma unroll
        for (int kk = 0; kk < 2; kk++) bf1[n][kk] = readB(cur, 2 + n, kk);
      __builtin_amdgcn_s_barrier();
      __builtin_amdgcn_s_setprio(1);
#pragma unroll
      for (int m = 0; m < 4; m++)
#pragma unroll
        for (int n = 0; n < 2; n++)
#pragma unroll
          for (int kk = 0; kk < 2; kk++)
            acc[m][n + 2] = __builtin_amdgcn_mfma_f32_16x16x32_bf16(
                af[m][kk], bf1[n][kk], acc[m][n + 2], 0, 0, 0);
      __builtin_amdgcn_s_setprio(0);
      __builtin_amdgcn_s_barrier();
      // ---- p2 ----
#pragma unroll
      for (int m = 0; m < 4; m++)
#pragma unroll
        for (int kk = 0; kk < 2; kk++) af[m][kk] = readA(cur, 4 + m, kk);
      if (hn) {
        stageB(nxt, kt1, 1, 0);      stageB(nxt, kt1, 1, 1);
        stageA(nxt, mb1, kt1, 1, 0); stageA(nxt, mb1, kt1, 1, 1);
      }
      __builtin_amdgcn_s_barrier();
      __builtin_amdgcn_s_setprio(1);
#pragma unroll
      for (int m = 0; m < 4; m++)
#pragma unroll
        for (int n = 0; n < 2; n++)
#pragma unroll
          for (int kk = 0; kk < 2; kk++)
            acc[m + 4][n + 2] = __builtin_amdgcn_mfma_f32_16x16x32_bf16(
                af[m][kk], bf1[n][kk], acc[m + 4][n + 2], 0, 0, 0);
#pragma unroll
      for (int m = 0; m < 4; m++)
#pragma unroll
        for (int n = 0; n < 2; n++)
#pragma unroll
          for (int kk = 0; kk < 2; kk++)
            acc[m + 4][n] = __builtin_amdgcn_mfma_f32_16x16x32_bf16(
                af[m][kk], bf0[n][kk], acc[m + 4][n], 0, 0, 0);
      __builtin_amdgcn_s_setprio(0);
      VMCNT(4);
      __builtin_amdgcn_s_barrier();
    }
#pragma unroll
    for (int mf = 0; mf < 8; mf++) {
      int rowb = m0 + mf * 32 + wr * 16 + g4 * 4;
#pragma unroll
      for (int nf = 0; nf < 4; nf++) {
        int col = n0 + nf * 64 + wc * 16 + r16;
        float b = bias[col];
#pragma unroll
        for (int j = 0; j < 4; j++)
          out[(size_t)(rowb + j) * N + col] = acc[mf][nf][j] + b;
      }
    }
#pragma unroll
    for (int mf = 0; mf < 8; mf++)
#pragma unroll
      for (int nf = 0; nf < 4; nf++) acc[mf][nf] = f32x4{0.f, 0.f, 0.f, 0.f};
  }
}

// ---------------- flash attention: 4-wave blocks, LDS-staged K ----------------
__global__ __launch_bounds__(256) void attn_kernel(const u16* __restrict__ qkv,
                                                   const u16* __restrict__ vt2,
                                                   u16* __restrict__ o) {
  __shared__ u16 Ks[2][32 * 64];
  __shared__ u16 pl[4][16 * 40];
  int qblk = blockIdx.x, bh = blockIdx.y;
  int b = bh >> 4, h = bh & 15;
  int tid = threadIdx.x, w = tid >> 6, lane = tid & 63;
  int r16 = lane & 15, g4 = lane >> 4;
  int q0 = qblk * 64 + w * 16;

  const u16* qrow = qkv + ((size_t)(b * SEQ) + q0 + r16) * QKVN + h * HD;
  vshort8 aq0 = *(const vshort8*)(qrow + g4 * 8);
  vshort8 aq1 = *(const vshort8*)(qrow + 32 + g4 * 8);

  float mrun[4], lrun[4];
  f32x4 accO[4];
#pragma unroll
  for (int j = 0; j < 4; j++) { mrun[j] = -1e30f; lrun[j] = 0.f; }
#pragma unroll
  for (int d = 0; d < 4; d++) accO[d] = f32x4{0.f, 0.f, 0.f, 0.f};

  int nkvT = qblk * 2 + 2;
  auto stageK = [&](int buf, int kt) {
    int row = tid >> 3;
    int slot = (tid & 7) ^ (row & 7);
    gll16(qkv + ((size_t)(b * SEQ) + kt * 32 + row) * QKVN + DIM + h * HD + slot * 8,
          &Ks[buf][w * 512 + lane * 8]);
  };
  stageK(0, 0);
  __syncthreads();
  int buf = 0;
  for (int kt = 0; kt < nkvT; kt++) {
    int kv0 = kt * 32;
    if (kt + 1 < nkvT) stageK(buf ^ 1, kt + 1);
    if (kv0 <= q0 + 15) {
      int row0 = r16, row1 = 16 + r16;
      vshort8 bk00 = *(const vshort8*)&Ks[buf][row0 * 64 + ((0 + g4) ^ (row0 & 7)) * 8];
      vshort8 bk01 = *(const vshort8*)&Ks[buf][row0 * 64 + ((4 + g4) ^ (row0 & 7)) * 8];
      vshort8 bk10 = *(const vshort8*)&Ks[buf][row1 * 64 + ((0 + g4) ^ (row1 & 7)) * 8];
      vshort8 bk11 = *(const vshort8*)&Ks[buf][row1 * 64 + ((4 + g4) ^ (row1 & 7)) * 8];
      f32x4 s0 = {}, s1 = {};
      s0 = __builtin_amdgcn_mfma_f32_16x16x32_bf16(aq0, bk00, s0, 0, 0, 0);
      s0 = __builtin_amdgcn_mfma_f32_16x16x32_bf16(aq1, bk01, s0, 0, 0, 0);
      s1 = __builtin_amdgcn_mfma_f32_16x16x32_bf16(aq0, bk10, s1, 0, 0, 0);
      s1 = __builtin_amdgcn_mfma_f32_16x16x32_bf16(aq1, bk11, s1, 0, 0, 0);

#pragma unroll
      for (int j = 0; j < 4; j++) {
        int qg = q0 + g4 * 4 + j;
        float x0 = s0[j] * 0.125f;
        float x1 = s1[j] * 0.125f;
        if (kv0 + r16 > qg) x0 = -1e30f;
        if (kv0 + 16 + r16 > qg) x1 = -1e30f;
        float mx = fmaxf(x0, x1);
#pragma unroll
        for (int mm = 1; mm < 16; mm <<= 1) mx = fmaxf(mx, __shfl_xor(mx, mm));
        float mnew = fmaxf(mrun[j], mx);
        float alpha = __expf(mrun[j] - mnew);
        float p0 = __expf(x0 - mnew);
        float p1 = __expf(x1 - mnew);
        float rs = p0 + p1;
#pragma unroll
        for (int mm = 1; mm < 16; mm <<= 1) rs += __shfl_xor(rs, mm);
        lrun[j] = lrun[j] * alpha + rs;
        mrun[j] = mnew;
#pragma unroll
        for (int d = 0; d < 4; d++) accO[d][j] *= alpha;
        pl[w][(g4 * 4 + j) * 40 + r16] = f2bf(p0);
        pl[w][(g4 * 4 + j) * 40 + 16 + r16] = f2bf(p1);
      }
      asm volatile("s_waitcnt lgkmcnt(0)" ::: "memory");
      vshort8 ap = *(const vshort8*)&pl[w][r16 * 40 + g4 * 8];
      const u16* vbase = vt2 + (((size_t)bh * (SEQ / 8) + (kv0 >> 3) + g4) * 64) * 8;
#pragma unroll
      for (int d = 0; d < 4; d++) {
        vshort8 bv = *(const vshort8*)(vbase + (size_t)(d * 16 + r16) * 8);
        accO[d] = __builtin_amdgcn_mfma_f32_16x16x32_bf16(ap, bv, accO[d], 0, 0, 0);
      }
    }
    __syncthreads();
    buf ^= 1;
  }

#pragma unroll
  for (int j = 0; j < 4; j++) {
    float inv = 1.f / lrun[j];
    int row = q0 + g4 * 4 + j;
#pragma unroll
    for (int d = 0; d < 4; d++)
      o[((size_t)(b * SEQ) + row) * DIM + h * HD + d * 16 + r16] =
          f2bf(accO[d][j] * inv);
  }
}

// ---------------- host ----------------
extern "C" void kernel_launch(void* const* d_in, const int* in_sizes, int n_in,
                              void* d_out, int out_size, void* d_ws,
                              size_t ws_size, hipStream_t stream) {
  const int* ids = (const int*)d_in[0];
  const float* emb = (const float*)d_in[1];
  const float* g1 = (const float*)d_in[2];
  const float* wq = (const float*)d_in[3];
  const float* bq = (const float*)d_in[4];
  const float* wk = (const float*)d_in[5];
  const float* bk = (const float*)d_in[6];
  const float* wv = (const float*)d_in[7];
  const float* bv = (const float*)d_in[8];
  const float* wo = (const float*)d_in[9];
  const float* bo = (const float*)d_in[10];
  const float* g2 = (const float*)d_in[11];
  const float* w1 = (const float*)d_in[12];
  const float* b1 = (const float*)d_in[13];
  const float* w2 = (const float*)d_in[14];
  const float* b2 = (const float*)d_in[15];
  const float* gf = (const float*)d_in[16];
  const float* head_w = (const float*)d_in[17];
  const float* head_b = (const float*)d_in[18];
  float* out = (float*)d_out;

  char* ws = (char*)d_ws;
  size_t off = 0;
  auto alloc = [&](size_t bytes) -> char* {
    char* p = ws + off;
    off += (bytes + 255) & ~(size_t)255;
    return p;
  };
  u16* wqkvT = (u16*)alloc((size_t)LAYERS * QKVN * DIM * 2);
  u16* woT = (u16*)alloc((size_t)LAYERS * DIM * DIM * 2);
  u16* w1T = (u16*)alloc((size_t)LAYERS * DIM * FFN * 2);
  u16* w2T = (u16*)alloc((size_t)LAYERS * DIM * FFN * 2);
  u16* headT = (u16*)alloc((size_t)VOCAB * DIM * 2);
  float* bqkv = (float*)alloc((size_t)LAYERS * QKVN * 4);
  float* x = (float*)alloc((size_t)ROWS * DIM * 4);
  u16* h = (u16*)alloc((size_t)ROWS * DIM * 2);
  u16* qkvb = (u16*)alloc((size_t)ROWS * QKVN * 2);
  u16* vtb = (u16*)alloc((size_t)ROWS * DIM * 2);
  u16* ob = (u16*)alloc((size_t)ROWS * DIM * 2);
  u16* tb = (u16*)alloc((size_t)ROWS * FFN * 2);
  float* P = (float*)alloc((size_t)4 * ROWS * DIM * 4);
  if (off > ws_size) return;

  prologue_kernel<<<16216, 256, 0, stream>>>(
      wq, wk, wv, wo, w1, w2, head_w, bq, bk, bv, ids, emb, g1, wqkvT, woT,
      w1T, w2T, headT, bqkv, x, h);

  for (int l = 0; l < LAYERS; l++) {
    gemm256x128p_kernel<1, 0, 0, 1>
        <<<(ROWS / 256) * (QKVN / 128), 512, 0, stream>>>(
            h, wqkvT + (size_t)l * QKVN * DIM, bqkv + (size_t)l * QKVN,
            qkvb, vtb, ROWS, QKVN, DIM);
    attn_kernel<<<dim3(SEQ / 64, BATCH * HEADS), 256, 0, stream>>>(qkvb, vtb, ob);
    gemm128sk_kernel<4>
        <<<4 * (ROWS / 128) * (DIM / 128), 256, 0, stream>>>(
            ob, woT + (size_t)l * DIM * DIM, P, ROWS, DIM, DIM);
    addnorm_kernel<4><<<ROWS, 256, 0, stream>>>(
        x, P, bo + (size_t)l * DIM, g2 + (size_t)l * DIM, h);
    gemm256x128p_kernel<1, 0, 1, 0>
        <<<(ROWS / 256) * (FFN / 128), 512, 0, stream>>>(
            h, w1T + (size_t)l * DIM * FFN, b1 + (size_t)l * FFN, tb, nullptr,
            ROWS, FFN, DIM);
    gemm128sk_kernel<4>
        <<<4 * (ROWS / 128) * (DIM / 128), 256, 0, stream>>>(
            tb, w2T + (size_t)l * DIM * FFN, P, ROWS, DIM, FFN);
    addnorm_kernel<4><<<ROWS, 256, 0, stream>>>(
        x, P, b2 + (size_t)l * DIM,
        (l == LAYERS - 1) ? gf : (g1 + (size_t)(l + 1) * DIM), h);
  }
  gemm256p_kernel<<<(VOCAB / 256) * 2, 512, 0, stream>>>(
      h, headT, head_b, out, ROWS, VOCAB, DIM);
}